// Round 5
// baseline (148.413 us; speedup 1.0000x reference)
//
#include <hip/hip_runtime.h>
#include <hip/hip_bf16.h>

typedef float f32x4 __attribute__((ext_vector_type(4)));
typedef __bf16 bf16x8 __attribute__((ext_vector_type(8)));
typedef __bf16 bf16x4 __attribute__((ext_vector_type(4)));
typedef short s16x4 __attribute__((ext_vector_type(4)));

constexpr int C = 256;
constexpr int N = 2304;           // 48*48 tokens per batch
constexpr int T = 2 * N;          // total tokens

#if __has_builtin(__builtin_amdgcn_exp2f)
#define EXP2F(x) __builtin_amdgcn_exp2f(x)
#else
#define EXP2F(x) exp2f(x)
#endif

__device__ __forceinline__ bf16x8 load_bf8(const __bf16* p) {
    return *reinterpret_cast<const bf16x8*>(p);
}

__device__ __forceinline__ f32x4 mfma32(bf16x8 a, bf16x8 b, f32x4 c) {
    return __builtin_amdgcn_mfma_f32_16x16x32_bf16(a, b, c, 0, 0, 0);
}

// K=16 MFMA: 4-element k-granules match the QK^T C/D output layout, so P feeds
// PV entirely in-register (no LDS redistribution). Verified correct in R4.
#if __has_builtin(__builtin_amdgcn_mfma_f32_16x16x16bf16_1k)
__device__ __forceinline__ f32x4 mfma16(bf16x4 a, bf16x4 b, f32x4 c) {
    return __builtin_amdgcn_mfma_f32_16x16x16bf16_1k(
        __builtin_bit_cast(s16x4, a), __builtin_bit_cast(s16x4, b), c, 0, 0, 0);
}
#else
__device__ __forceinline__ f32x4 mfma16(bf16x4 a, bf16x4 b, f32x4 c) {
    f32x4 d;
    asm volatile("v_mfma_f32_16x16x16_bf16 %0, %1, %2, %3"
                 : "=v"(d) : "v"(a), "v"(b), "v"(c));
    return d;
}
#endif

// ---------------- kernel 0: convert Wq/Wk/Wv/Wo to bf16 ----------------
__global__ void wconv_kernel(const float* __restrict__ Wq, const float* __restrict__ Wk,
                             const float* __restrict__ Wv, const float* __restrict__ Wo,
                             __bf16* __restrict__ Wb) {
    const float* srcs[4] = {Wq, Wk, Wv, Wo};
    int m = blockIdx.x >> 6;
    int idx = (blockIdx.x & 63) * 256 + threadIdx.x;   // [0, 16384)
    float4 v = reinterpret_cast<const float4*>(srcs[m])[idx];
    bf16x4 o = { (__bf16)v.x, (__bf16)v.y, (__bf16)v.z, (__bf16)v.w };
    reinterpret_cast<bf16x4*>(Wb + m * 65536)[idx] = o;
}

// ---------------- kernel 1: gate + transpose to token-major bf16 ----------------
__global__ void prep_kernel(const float* __restrict__ x, const float* __restrict__ u,
                            const float* __restrict__ Wg, const float* __restrict__ bg,
                            __bf16* __restrict__ xT, __bf16* __restrict__ gxT) {
    __shared__ float tile[64][65];
    int b = blockIdx.z, c0 = blockIdx.y * 64, n0 = blockIdx.x * 64;
    int t = threadIdx.x;
    const float* xp = x + (b * C + c0) * N + n0;
    #pragma unroll
    for (int r = 0; r < 16; ++r) {
        int cl = r * 4 + (t >> 6);
        int nl = t & 63;
        tile[cl][nl] = xp[cl * N + nl];
    }
    __syncthreads();
    int cq = (t & 15) * 4;
    #pragma unroll
    for (int it = 0; it < 4; ++it) {
        int nl = it * 16 + (t >> 4);
        float uv = u[b * N + n0 + nl];
        bf16x4 xo, go;
        #pragma unroll
        for (int j = 0; j < 4; ++j) {
            int c = c0 + cq + j;
            float xv = tile[cq + j][nl];
            float gate = 1.0f - (Wg[c] * uv + bg[c]);
            xo[j] = (__bf16)xv;
            go[j] = (__bf16)(xv * gate);
        }
        int tok = b * N + n0 + nl;
        *reinterpret_cast<bf16x4*>(xT + (long)tok * C + c0 + cq) = xo;
        *reinterpret_cast<bf16x4*>(gxT + (long)tok * C + c0 + cq) = go;
    }
}

// ---------------- kernel 2: QKV projections (bf16 MFMA) ----------------
// Q[bh][n][d], K[bh][m][d] (pre-scaled by SCALE*log2e*(1-u[m])), V[bh][d][n]
__global__ __launch_bounds__(256) void qkv_kernel(const __bf16* __restrict__ Wb,
    const __bf16* __restrict__ xT, const __bf16* __restrict__ gxT,
    const float* __restrict__ bq, const float* __restrict__ bk, const float* __restrict__ bv,
    const float* __restrict__ u,
    __bf16* __restrict__ Q, __bf16* __restrict__ K, __bf16* __restrict__ V) {
    int proj = blockIdx.z;            // 0=q,1=k,2=v
    int o0 = blockIdx.y * 64;
    int t0 = blockIdx.x * 32;
    int wave = threadIdx.x >> 6, lane = threadIdx.x & 63;
    int g = lane >> 4, r = lane & 15;
    int ow = o0 + wave * 16;
    const __bf16* W = Wb + proj * 65536;
    const __bf16* inp = (proj == 2) ? xT : gxT;
    f32x4 acc[2] = {};
    for (int k = 0; k < 8; ++k) {
        bf16x8 a = load_bf8(W + (ow + r) * C + k * 32 + g * 8);
        #pragma unroll
        for (int tb = 0; tb < 2; ++tb) {
            bf16x8 bfr = load_bf8(inp + (long)(t0 + tb * 16 + r) * C + k * 32 + g * 8);
            acc[tb] = mfma32(a, bfr, acc[tb]);
        }
    }
    const float* bias = (proj == 0) ? bq : (proj == 1) ? bk : bv;
    float bvw[4];
    #pragma unroll
    for (int i = 0; i < 4; ++i) bvw[i] = bias[ow + g * 4 + i];
    int h = ow >> 5, d0 = (ow & 31) + g * 4;
    const float SC = 0.17677669529663687f * 1.4426950408889634f;  // SCALE * log2(e)
    #pragma unroll
    for (int tb = 0; tb < 2; ++tb) {
        int t = t0 + tb * 16 + r;
        int b = t / N, n = t % N;
        if (proj == 2) {
            #pragma unroll
            for (int i = 0; i < 4; ++i)
                V[((long)(b * 8 + h) * 32 + d0 + i) * N + n] = (__bf16)(acc[tb][i] + bvw[i]);
        } else {
            bf16x4 outv;
            if (proj == 1) {
                float scale = SC * (1.0f - u[t]);
                #pragma unroll
                for (int i = 0; i < 4; ++i) outv[i] = (__bf16)((acc[tb][i] + bvw[i]) * scale);
            } else {
                #pragma unroll
                for (int i = 0; i < 4; ++i) outv[i] = (__bf16)(acc[tb][i] + bvw[i]);
            }
            __bf16* dst = (proj == 0) ? Q : K;
            *reinterpret_cast<bf16x4*>(dst + ((long)(b * 8 + h) * N + n) * 32 + d0) = outv;
        }
    }
}

// ---------------- kernel 3: flash attention ----------------
// 16q/block, 4-way key-split (2304 blocks -> 9216 waves, 8/SIMD target),
// in-register P via K=16 PV MFMA, XCD-pinned grid, no in-loop LDS.
// VGPR budget <=64 enforced: phase order K-load -> QK -> V-load -> exp2 -> PV.
__global__ __launch_bounds__(256, 8) void attn_kernel(const __bf16* __restrict__ Q,
    const __bf16* __restrict__ K, const __bf16* __restrict__ V,
    __bf16* __restrict__ aoT) {
    __shared__ float po[4][16][32];    // per-wave partial O (16B-granule XOR swizzled)
    __shared__ float lds_l[4][16];     // per-wave partial denominator
    int id = blockIdx.x;
    int rest = id >> 3;                // [0, 288)
    int qc = rest % 144;
    int bh = (id & 7) + 8 * (rest / 144);
    int wave = threadIdx.x >> 6, lane = threadIdx.x & 63;
    int g = lane >> 4, r = lane & 15;
    int q0 = qc * 16;
    const __bf16* Qb = Q + (long)bh * N * 32;
    const __bf16* Kb = K + (long)bh * N * 32;
    const __bf16* Vb = V + (long)bh * 32 * N;
    bf16x8 qf = load_bf8(Qb + (q0 + r) * 32 + g * 8);   // B-frag: Q^T[d][q]
    int mbase = wave * 576;
    f32x4 oa0 = {}, oa1 = {};
    float lr = 0.0f;
    for (int it = 0; it < 9; ++it) {
        int m0 = mbase + it * 64;
        // K A-frags for this iter
        bf16x8 kc0 = load_bf8(Kb + (m0 +  0 + r) * 32 + g * 8);
        bf16x8 kc1 = load_bf8(Kb + (m0 + 16 + r) * 32 + g * 8);
        bf16x8 kc2 = load_bf8(Kb + (m0 + 32 + r) * 32 + g * 8);
        bf16x8 kc3 = load_bf8(Kb + (m0 + 48 + r) * 32 + g * 8);
        f32x4 z = {};
        __builtin_amdgcn_s_setprio(1);
        f32x4 s0 = mfma32(kc0, qf, z);   // S^T: lane(g,r) q=r, m=t*16+g*4+i
        f32x4 s1 = mfma32(kc1, qf, z);
        f32x4 s2 = mfma32(kc2, qf, z);
        f32x4 s3 = mfma32(kc3, qf, z);
        __builtin_amdgcn_s_setprio(0);
        // V A-frags for K=16 PV (loaded after QK so kc regs are dead first)
        bf16x4 vf[4][2];
        #pragma unroll
        for (int t = 0; t < 4; ++t)
            #pragma unroll
            for (int dt = 0; dt < 2; ++dt)
                vf[t][dt] = *reinterpret_cast<const bf16x4*>(Vb + (dt * 16 + r) * N + m0 + t * 16 + g * 4);
        // exp2 + pack (scores pre-scaled by log2e)
        bf16x4 pa[4];
        f32x4 sv[4] = {s0, s1, s2, s3};
        #pragma unroll
        for (int t = 0; t < 4; ++t) {
            #pragma unroll
            for (int i = 0; i < 4; ++i) {
                float p = EXP2F(sv[t][i]);
                lr += p;
                pa[t][i] = (__bf16)p;
            }
        }
        __builtin_amdgcn_s_setprio(1);
        #pragma unroll
        for (int t = 0; t < 4; ++t) {
            oa0 = mfma16(vf[t][0], pa[t], oa0);
            oa1 = mfma16(vf[t][1], pa[t], oa1);
        }
        __builtin_amdgcn_s_setprio(0);
    }
    // per-wave partial denominator (per query row r)
    float lt = lr;
    lt += __shfl_xor(lt, 16, 64);
    lt += __shfl_xor(lt, 32, 64);
    // swizzled stash: content-granule gi lives at physical granule gi^(r&7)
    char* pob = reinterpret_cast<char*>(&po[wave][0][0]);
    int sg0 = g ^ (r & 7);
    *reinterpret_cast<f32x4*>(pob + r * 128 + sg0 * 16) = oa0;
    *reinterpret_cast<f32x4*>(pob + r * 128 + (sg0 ^ 4) * 16) = oa1;
    if (g == 0) lds_l[wave][r] = lt;
    __syncthreads();
    // combine 4 key-chunks, normalize, write (512 outputs, 4 per thread)
    int tid = threadIdx.x;
    if (tid < 128) {
        int qq = tid >> 3;          // 0..15
        int gi = tid & 7;           // content granule -> d4 = gi*4
        int sg = gi ^ (qq & 7);
        f32x4 sum = {};
        float l = 0.0f;
        #pragma unroll
        for (int w = 0; w < 4; ++w) {
            sum += *reinterpret_cast<const f32x4*>(
                reinterpret_cast<const char*>(&po[w][0][0]) + qq * 128 + sg * 16);
            l += lds_l[w][qq];
        }
        float inv = 1.0f / l;
        bf16x4 ov;
        #pragma unroll
        for (int i = 0; i < 4; ++i) ov[i] = (__bf16)(sum[i] * inv);
        int b = bh >> 3, h = bh & 7;
        *reinterpret_cast<bf16x4*>(aoT + (long)(b * N + q0 + qq) * C + h * 32 + gi * 4) = ov;
    }
}

// ---------------- kernel 4: output projection + bias + residual ----------------
__global__ __launch_bounds__(256) void outp_kernel(const __bf16* __restrict__ Wb,
    const __bf16* __restrict__ aoT, const float* __restrict__ bo,
    const float* __restrict__ x, float* __restrict__ out) {
    int o0 = blockIdx.y * 64;
    int t0 = blockIdx.x * 32;
    int wave = threadIdx.x >> 6, lane = threadIdx.x & 63;
    int g = lane >> 4, r = lane & 15;
    int ow = o0 + wave * 16;
    const __bf16* W = Wb + 3 * 65536;   // Wo
    f32x4 acc[2] = {};
    for (int k = 0; k < 8; ++k) {
        bf16x8 a = load_bf8(W + (ow + r) * C + k * 32 + g * 8);
        #pragma unroll
        for (int tb = 0; tb < 2; ++tb) {
            bf16x8 bfr = load_bf8(aoT + (long)(t0 + tb * 16 + r) * C + k * 32 + g * 8);
            acc[tb] = mfma32(a, bfr, acc[tb]);
        }
    }
    float bvw[4];
    #pragma unroll
    for (int i = 0; i < 4; ++i) bvw[i] = bo[ow + g * 4 + i];
    #pragma unroll
    for (int tb = 0; tb < 2; ++tb) {
        int t = t0 + tb * 16 + r;
        int b = t / N, n = t % N;
        #pragma unroll
        for (int i = 0; i < 4; ++i) {
            long idx = ((long)b * C + ow + g * 4 + i) * N + n;
            out[idx] = acc[tb][i] + bvw[i] + x[idx];
        }
    }
}

extern "C" void kernel_launch(void* const* d_in, const int* in_sizes, int n_in,
                              void* d_out, int out_size, void* d_ws, size_t ws_size,
                              hipStream_t stream) {
    const float* x  = (const float*)d_in[0];
    const float* u  = (const float*)d_in[1];
    const float* Wq = (const float*)d_in[2];
    const float* bq = (const float*)d_in[3];
    const float* Wk = (const float*)d_in[4];
    const float* bk = (const float*)d_in[5];
    const float* Wv = (const float*)d_in[6];
    const float* bv = (const float*)d_in[7];
    const float* Wg = (const float*)d_in[8];
    const float* bg = (const float*)d_in[9];
    const float* Wo = (const float*)d_in[10];
    const float* bo = (const float*)d_in[11];
    float* out = (float*)d_out;

    char* ws = (char*)d_ws;
    size_t off = 0;
    auto alloc = [&](size_t bytes) {
        char* p = ws + off;
        off += (bytes + 255) & ~(size_t)255;
        return p;
    };
    __bf16* Wb  = (__bf16*)alloc((size_t)4 * 65536 * 2);
    __bf16* xT  = (__bf16*)alloc((size_t)T * C * 2);
    __bf16* gxT = (__bf16*)alloc((size_t)T * C * 2);
    __bf16* Qb  = (__bf16*)alloc((size_t)16 * N * 32 * 2);
    __bf16* Kb  = (__bf16*)alloc((size_t)16 * N * 32 * 2);
    __bf16* Vb  = (__bf16*)alloc((size_t)16 * N * 32 * 2);
    __bf16* aoT = (__bf16*)alloc((size_t)T * C * 2);

    wconv_kernel<<<256, 256, 0, stream>>>(Wq, Wk, Wv, Wo, Wb);
    prep_kernel<<<dim3(36, 4, 2), 256, 0, stream>>>(x, u, Wg, bg, xT, gxT);
    qkv_kernel<<<dim3(144, 4, 3), 256, 0, stream>>>(Wb, xT, gxT, bq, bk, bv, u, Qb, Kb, Vb);
    attn_kernel<<<2304, 256, 0, stream>>>(Qb, Kb, Vb, aoT);
    outp_kernel<<<dim3(144, 4), 256, 0, stream>>>(Wb, aoT, bo, x, out);
}

// Round 6
// 137.898 us; speedup vs baseline: 1.0763x; 1.0763x over previous
//
#include <hip/hip_runtime.h>
#include <hip/hip_bf16.h>

typedef float f32x4 __attribute__((ext_vector_type(4)));
typedef __bf16 bf16x8 __attribute__((ext_vector_type(8)));
typedef __bf16 bf16x4 __attribute__((ext_vector_type(4)));
typedef short s16x4 __attribute__((ext_vector_type(4)));

constexpr int C = 256;
constexpr int N = 2304;           // 48*48 tokens per batch
constexpr int T = 2 * N;          // total tokens

#if __has_builtin(__builtin_amdgcn_exp2f)
#define EXP2F(x) __builtin_amdgcn_exp2f(x)
#else
#define EXP2F(x) exp2f(x)
#endif

__device__ __forceinline__ bf16x8 load_bf8(const __bf16* p) {
    return *reinterpret_cast<const bf16x8*>(p);
}

__device__ __forceinline__ f32x4 mfma32(bf16x8 a, bf16x8 b, f32x4 c) {
    return __builtin_amdgcn_mfma_f32_16x16x32_bf16(a, b, c, 0, 0, 0);
}

// K=16 MFMA: 4-element k-granules match the QK^T C/D output layout, so P feeds
// PV entirely in-register (no LDS redistribution). Verified correct in R4.
#if __has_builtin(__builtin_amdgcn_mfma_f32_16x16x16bf16_1k)
__device__ __forceinline__ f32x4 mfma16(bf16x4 a, bf16x4 b, f32x4 c) {
    return __builtin_amdgcn_mfma_f32_16x16x16bf16_1k(
        __builtin_bit_cast(s16x4, a), __builtin_bit_cast(s16x4, b), c, 0, 0, 0);
}
#else
__device__ __forceinline__ f32x4 mfma16(bf16x4 a, bf16x4 b, f32x4 c) {
    f32x4 d;
    asm volatile("v_mfma_f32_16x16x16_bf16 %0, %1, %2, %3"
                 : "=v"(d) : "v"(a), "v"(b), "v"(c));
    return d;
}
#endif

// ---------------- kernel 0: convert Wq/Wk/Wv/Wo to bf16 ----------------
__global__ void wconv_kernel(const float* __restrict__ Wq, const float* __restrict__ Wk,
                             const float* __restrict__ Wv, const float* __restrict__ Wo,
                             __bf16* __restrict__ Wb) {
    const float* srcs[4] = {Wq, Wk, Wv, Wo};
    int m = blockIdx.x >> 6;
    int idx = (blockIdx.x & 63) * 256 + threadIdx.x;   // [0, 16384)
    float4 v = reinterpret_cast<const float4*>(srcs[m])[idx];
    bf16x4 o = { (__bf16)v.x, (__bf16)v.y, (__bf16)v.z, (__bf16)v.w };
    reinterpret_cast<bf16x4*>(Wb + m * 65536)[idx] = o;
}

// ---------------- kernel 1: gate + transpose to token-major bf16 ----------------
__global__ void prep_kernel(const float* __restrict__ x, const float* __restrict__ u,
                            const float* __restrict__ Wg, const float* __restrict__ bg,
                            __bf16* __restrict__ xT, __bf16* __restrict__ gxT) {
    __shared__ float tile[64][65];
    int b = blockIdx.z, c0 = blockIdx.y * 64, n0 = blockIdx.x * 64;
    int t = threadIdx.x;
    const float* xp = x + (b * C + c0) * N + n0;
    #pragma unroll
    for (int r = 0; r < 16; ++r) {
        int cl = r * 4 + (t >> 6);
        int nl = t & 63;
        tile[cl][nl] = xp[cl * N + nl];
    }
    __syncthreads();
    int cq = (t & 15) * 4;
    #pragma unroll
    for (int it = 0; it < 4; ++it) {
        int nl = it * 16 + (t >> 4);
        float uv = u[b * N + n0 + nl];
        bf16x4 xo, go;
        #pragma unroll
        for (int j = 0; j < 4; ++j) {
            int c = c0 + cq + j;
            float xv = tile[cq + j][nl];
            float gate = 1.0f - (Wg[c] * uv + bg[c]);
            xo[j] = (__bf16)xv;
            go[j] = (__bf16)(xv * gate);
        }
        int tok = b * N + n0 + nl;
        *reinterpret_cast<bf16x4*>(xT + (long)tok * C + c0 + cq) = xo;
        *reinterpret_cast<bf16x4*>(gxT + (long)tok * C + c0 + cq) = go;
    }
}

// ---------------- kernel 2: QKV projections (bf16 MFMA) ----------------
// Q[bh][n][d], K[bh][m][d] (pre-scaled by SCALE*log2e*(1-u[m])), V[bh][d][n]
__global__ __launch_bounds__(256) void qkv_kernel(const __bf16* __restrict__ Wb,
    const __bf16* __restrict__ xT, const __bf16* __restrict__ gxT,
    const float* __restrict__ bq, const float* __restrict__ bk, const float* __restrict__ bv,
    const float* __restrict__ u,
    __bf16* __restrict__ Q, __bf16* __restrict__ K, __bf16* __restrict__ V) {
    int proj = blockIdx.z;            // 0=q,1=k,2=v
    int o0 = blockIdx.y * 64;
    int t0 = blockIdx.x * 32;
    int wave = threadIdx.x >> 6, lane = threadIdx.x & 63;
    int g = lane >> 4, r = lane & 15;
    int ow = o0 + wave * 16;
    const __bf16* W = Wb + proj * 65536;
    const __bf16* inp = (proj == 2) ? xT : gxT;
    f32x4 acc[2] = {};
    for (int k = 0; k < 8; ++k) {
        bf16x8 a = load_bf8(W + (ow + r) * C + k * 32 + g * 8);
        #pragma unroll
        for (int tb = 0; tb < 2; ++tb) {
            bf16x8 bfr = load_bf8(inp + (long)(t0 + tb * 16 + r) * C + k * 32 + g * 8);
            acc[tb] = mfma32(a, bfr, acc[tb]);
        }
    }
    const float* bias = (proj == 0) ? bq : (proj == 1) ? bk : bv;
    float bvw[4];
    #pragma unroll
    for (int i = 0; i < 4; ++i) bvw[i] = bias[ow + g * 4 + i];
    int h = ow >> 5, d0 = (ow & 31) + g * 4;
    const float SC = 0.17677669529663687f * 1.4426950408889634f;  // SCALE * log2(e)
    #pragma unroll
    for (int tb = 0; tb < 2; ++tb) {
        int t = t0 + tb * 16 + r;
        int b = t / N, n = t % N;
        if (proj == 2) {
            #pragma unroll
            for (int i = 0; i < 4; ++i)
                V[((long)(b * 8 + h) * 32 + d0 + i) * N + n] = (__bf16)(acc[tb][i] + bvw[i]);
        } else {
            bf16x4 outv;
            if (proj == 1) {
                float scale = SC * (1.0f - u[t]);
                #pragma unroll
                for (int i = 0; i < 4; ++i) outv[i] = (__bf16)((acc[tb][i] + bvw[i]) * scale);
            } else {
                #pragma unroll
                for (int i = 0; i < 4; ++i) outv[i] = (__bf16)(acc[tb][i] + bvw[i]);
            }
            __bf16* dst = (proj == 0) ? Q : K;
            *reinterpret_cast<bf16x4*>(dst + ((long)(b * 8 + h) * N + n) * 32 + d0) = outv;
        }
    }
}

// ---------------- kernel 3: flash attention ----------------
// 16q/block, 4-way key-split (2304 blocks), in-register P via K=16 PV MFMA,
// XCD-pinned grid, no in-loop LDS. launch_bounds(256,4): cap 128 VGPR so the
// full load batch (8 V + 4 next-K) stays in flight (R5's (256,8) -> 32 VGPR
// serialized all loads: 3100 cyc/wave-iter). Denominator via ones-row MFMA.
__global__ __launch_bounds__(256, 4) void attn_kernel(const __bf16* __restrict__ Q,
    const __bf16* __restrict__ K, const __bf16* __restrict__ V,
    __bf16* __restrict__ aoT) {
    __shared__ float po[4][16][32];    // per-wave partial O (16B-granule XOR swizzled)
    __shared__ float lds_l[4][16];     // per-wave partial denominator
    int id = blockIdx.x;
    int rest = id >> 3;                // [0, 288)
    int qc = rest % 144;
    int bh = (id & 7) + 8 * (rest / 144);
    int wave = threadIdx.x >> 6, lane = threadIdx.x & 63;
    int g = lane >> 4, r = lane & 15;
    int q0 = qc * 16;
    const __bf16* Qb = Q + (long)bh * N * 32;
    bf16x8 qf = load_bf8(Qb + (q0 + r) * 32 + g * 8);   // B-frag: Q^T[d][q]
    // per-lane base pointers (bumped each iter -> minimal addr VALU, imm offsets)
    const __bf16* Kp  = K + (long)bh * N * 32 + (wave * 576 + r) * 32 + g * 8;
    const __bf16* Vp0 = V + (long)bh * 32 * N + (     r) * N + wave * 576 + g * 4;
    const __bf16* Vp1 = V + (long)bh * 32 * N + (16 + r) * N + wave * 576 + g * 4;
    bf16x4 onesv;
    #pragma unroll
    for (int i = 0; i < 4; ++i) onesv[i] = (__bf16)1.0f;
    f32x4 oa0 = {}, oa1 = {}, oal = {};
    // K frags for iter 0
    bf16x8 kc0 = load_bf8(Kp);
    bf16x8 kc1 = load_bf8(Kp + 16 * 32);
    bf16x8 kc2 = load_bf8(Kp + 32 * 32);
    bf16x8 kc3 = load_bf8(Kp + 48 * 32);
    for (int it = 0; it < 9; ++it) {
        // ---- batch ALL loads first: V for this iter, K for next iter ----
        bf16x4 vf00 = *reinterpret_cast<const bf16x4*>(Vp0);
        bf16x4 vf10 = *reinterpret_cast<const bf16x4*>(Vp0 + 16);
        bf16x4 vf20 = *reinterpret_cast<const bf16x4*>(Vp0 + 32);
        bf16x4 vf30 = *reinterpret_cast<const bf16x4*>(Vp0 + 48);
        bf16x4 vf01 = *reinterpret_cast<const bf16x4*>(Vp1);
        bf16x4 vf11 = *reinterpret_cast<const bf16x4*>(Vp1 + 16);
        bf16x4 vf21 = *reinterpret_cast<const bf16x4*>(Vp1 + 32);
        bf16x4 vf31 = *reinterpret_cast<const bf16x4*>(Vp1 + 48);
        const __bf16* Kn = Kp + ((it == 8) ? 0 : 64 * 32);   // clamp last prefetch
        bf16x8 kn0 = load_bf8(Kn);
        bf16x8 kn1 = load_bf8(Kn + 16 * 32);
        bf16x8 kn2 = load_bf8(Kn + 32 * 32);
        bf16x8 kn3 = load_bf8(Kn + 48 * 32);
        // ---- QK^T on current K (already resident from prefetch) ----
        f32x4 z = {};
        __builtin_amdgcn_s_setprio(1);
        f32x4 s0 = mfma32(kc0, qf, z);   // S^T: lane(g,r) q=r, m=t*16+g*4+i
        f32x4 s1 = mfma32(kc1, qf, z);
        f32x4 s2 = mfma32(kc2, qf, z);
        f32x4 s3 = mfma32(kc3, qf, z);
        __builtin_amdgcn_s_setprio(0);
        // ---- exp2 + pack (covers V-load latency) ----
        bf16x4 pa0, pa1, pa2, pa3;
        #pragma unroll
        for (int i = 0; i < 4; ++i) pa0[i] = (__bf16)EXP2F(s0[i]);
        #pragma unroll
        for (int i = 0; i < 4; ++i) pa1[i] = (__bf16)EXP2F(s1[i]);
        #pragma unroll
        for (int i = 0; i < 4; ++i) pa2[i] = (__bf16)EXP2F(s2[i]);
        #pragma unroll
        for (int i = 0; i < 4; ++i) pa3[i] = (__bf16)EXP2F(s3[i]);
        // ---- PV (K=16, in-register P) + denominator via ones-row ----
        __builtin_amdgcn_s_setprio(1);
        oa0 = mfma16(vf00, pa0, oa0);
        oa1 = mfma16(vf01, pa0, oa1);
        oal = mfma16(onesv, pa0, oal);
        oa0 = mfma16(vf10, pa1, oa0);
        oa1 = mfma16(vf11, pa1, oa1);
        oal = mfma16(onesv, pa1, oal);
        oa0 = mfma16(vf20, pa2, oa0);
        oa1 = mfma16(vf21, pa2, oa1);
        oal = mfma16(onesv, pa2, oal);
        oa0 = mfma16(vf30, pa3, oa0);
        oa1 = mfma16(vf31, pa3, oa1);
        oal = mfma16(onesv, pa3, oal);
        __builtin_amdgcn_s_setprio(0);
        kc0 = kn0; kc1 = kn1; kc2 = kn2; kc3 = kn3;
        Kp = Kn;
        Vp0 += 64;
        Vp1 += 64;
    }
    // oal: every row of the ones-MFMA output equals the denom for column q=r,
    // so each lane already holds the full per-wave denominator — no shuffles.
    // swizzled stash: content-granule gi lives at physical granule gi^(r&7)
    char* pob = reinterpret_cast<char*>(&po[wave][0][0]);
    int sg0 = g ^ (r & 7);
    *reinterpret_cast<f32x4*>(pob + r * 128 + sg0 * 16) = oa0;
    *reinterpret_cast<f32x4*>(pob + r * 128 + (sg0 ^ 4) * 16) = oa1;
    if (g == 0) lds_l[wave][r] = oal[0];
    __syncthreads();
    // combine 4 key-chunks, normalize, write (512 outputs, 4 per thread)
    int tid = threadIdx.x;
    if (tid < 128) {
        int qq = tid >> 3;          // 0..15
        int gi = tid & 7;           // content granule -> d4 = gi*4
        int sg = gi ^ (qq & 7);
        f32x4 sum = {};
        float l = 0.0f;
        #pragma unroll
        for (int w = 0; w < 4; ++w) {
            sum += *reinterpret_cast<const f32x4*>(
                reinterpret_cast<const char*>(&po[w][0][0]) + qq * 128 + sg * 16);
            l += lds_l[w][qq];
        }
        float inv = 1.0f / l;
        bf16x4 ov;
        #pragma unroll
        for (int i = 0; i < 4; ++i) ov[i] = (__bf16)(sum[i] * inv);
        int b = bh >> 3, h = bh & 7;
        *reinterpret_cast<bf16x4*>(aoT + (long)(b * N + q0 + qq) * C + h * 32 + gi * 4) = ov;
    }
}

// ---------------- kernel 4: output projection + bias + residual ----------------
__global__ __launch_bounds__(256) void outp_kernel(const __bf16* __restrict__ Wb,
    const __bf16* __restrict__ aoT, const float* __restrict__ bo,
    const float* __restrict__ x, float* __restrict__ out) {
    int o0 = blockIdx.y * 64;
    int t0 = blockIdx.x * 32;
    int wave = threadIdx.x >> 6, lane = threadIdx.x & 63;
    int g = lane >> 4, r = lane & 15;
    int ow = o0 + wave * 16;
    const __bf16* W = Wb + 3 * 65536;   // Wo
    f32x4 acc[2] = {};
    for (int k = 0; k < 8; ++k) {
        bf16x8 a = load_bf8(W + (ow + r) * C + k * 32 + g * 8);
        #pragma unroll
        for (int tb = 0; tb < 2; ++tb) {
            bf16x8 bfr = load_bf8(aoT + (long)(t0 + tb * 16 + r) * C + k * 32 + g * 8);
            acc[tb] = mfma32(a, bfr, acc[tb]);
        }
    }
    float bvw[4];
    #pragma unroll
    for (int i = 0; i < 4; ++i) bvw[i] = bo[ow + g * 4 + i];
    #pragma unroll
    for (int tb = 0; tb < 2; ++tb) {
        int t = t0 + tb * 16 + r;
        int b = t / N, n = t % N;
        #pragma unroll
        for (int i = 0; i < 4; ++i) {
            long idx = ((long)b * C + ow + g * 4 + i) * N + n;
            out[idx] = acc[tb][i] + bvw[i] + x[idx];
        }
    }
}

extern "C" void kernel_launch(void* const* d_in, const int* in_sizes, int n_in,
                              void* d_out, int out_size, void* d_ws, size_t ws_size,
                              hipStream_t stream) {
    const float* x  = (const float*)d_in[0];
    const float* u  = (const float*)d_in[1];
    const float* Wq = (const float*)d_in[2];
    const float* bq = (const float*)d_in[3];
    const float* Wk = (const float*)d_in[4];
    const float* bk = (const float*)d_in[5];
    const float* Wv = (const float*)d_in[6];
    const float* bv = (const float*)d_in[7];
    const float* Wg = (const float*)d_in[8];
    const float* bg = (const float*)d_in[9];
    const float* Wo = (const float*)d_in[10];
    const float* bo = (const float*)d_in[11];
    float* out = (float*)d_out;

    char* ws = (char*)d_ws;
    size_t off = 0;
    auto alloc = [&](size_t bytes) {
        char* p = ws + off;
        off += (bytes + 255) & ~(size_t)255;
        return p;
    };
    __bf16* Wb  = (__bf16*)alloc((size_t)4 * 65536 * 2);
    __bf16* xT  = (__bf16*)alloc((size_t)T * C * 2);
    __bf16* gxT = (__bf16*)alloc((size_t)T * C * 2);
    __bf16* Qb  = (__bf16*)alloc((size_t)16 * N * 32 * 2);
    __bf16* Kb  = (__bf16*)alloc((size_t)16 * N * 32 * 2);
    __bf16* Vb  = (__bf16*)alloc((size_t)16 * N * 32 * 2);
    __bf16* aoT = (__bf16*)alloc((size_t)T * C * 2);

    wconv_kernel<<<256, 256, 0, stream>>>(Wq, Wk, Wv, Wo, Wb);
    prep_kernel<<<dim3(36, 4, 2), 256, 0, stream>>>(x, u, Wg, bg, xT, gxT);
    qkv_kernel<<<dim3(144, 4, 3), 256, 0, stream>>>(Wb, xT, gxT, bq, bk, bv, u, Qb, Kb, Vb);
    attn_kernel<<<2304, 256, 0, stream>>>(Qb, Kb, Vb, aoT);
    outp_kernel<<<dim3(144, 4), 256, 0, stream>>>(Wb, aoT, bo, x, out);
}

// Round 7
// 81.155 us; speedup vs baseline: 1.8288x; 1.6992x over previous
//
#include <hip/hip_runtime.h>
#include <hip/hip_bf16.h>

typedef float f32x4 __attribute__((ext_vector_type(4)));
typedef __bf16 bf16x8 __attribute__((ext_vector_type(8)));
typedef __bf16 bf16x4 __attribute__((ext_vector_type(4)));
typedef short s16x4 __attribute__((ext_vector_type(4)));

constexpr int C = 256;
constexpr int N = 2304;           // 48*48 tokens per batch
constexpr int T = 2 * N;          // total tokens

#if __has_builtin(__builtin_amdgcn_exp2f)
#define EXP2F(x) __builtin_amdgcn_exp2f(x)
#else
#define EXP2F(x) exp2f(x)
#endif

__device__ __forceinline__ bf16x8 load_bf8(const __bf16* p) {
    return *reinterpret_cast<const bf16x8*>(p);
}

__device__ __forceinline__ f32x4 mfma32(bf16x8 a, bf16x8 b, f32x4 c) {
    return __builtin_amdgcn_mfma_f32_16x16x32_bf16(a, b, c, 0, 0, 0);
}

// K=16 MFMA: 4-element k-granules match the QK^T C/D output layout, so P feeds
// PV entirely in-register (no LDS redistribution). Verified correct R4-R6.
#if __has_builtin(__builtin_amdgcn_mfma_f32_16x16x16bf16_1k)
__device__ __forceinline__ f32x4 mfma16(bf16x4 a, bf16x4 b, f32x4 c) {
    return __builtin_amdgcn_mfma_f32_16x16x16bf16_1k(
        __builtin_bit_cast(s16x4, a), __builtin_bit_cast(s16x4, b), c, 0, 0, 0);
}
#else
__device__ __forceinline__ f32x4 mfma16(bf16x4 a, bf16x4 b, f32x4 c) {
    f32x4 d;
    asm volatile("v_mfma_f32_16x16x16_bf16 %0, %1, %2, %3"
                 : "=v"(d) : "v"(a), "v"(b), "v"(c));
    return d;
}
#endif

// async global->LDS, 16B per lane; dest = wave-uniform base + lane*16
__device__ __forceinline__ void gload_lds16(const __bf16* g, __bf16* l) {
    __builtin_amdgcn_global_load_lds(
        (const __attribute__((address_space(1))) void*)g,
        (__attribute__((address_space(3))) void*)l, 16, 0, 0);
}

#define VMCNT2() asm volatile("s_waitcnt vmcnt(2)" ::: "memory")
#define VMCNT0() asm volatile("s_waitcnt vmcnt(0)" ::: "memory")
#define LGKM0()  asm volatile("s_waitcnt lgkmcnt(0)" ::: "memory")

// ---------------- kernel 0: convert Wq/Wk/Wv/Wo to bf16 ----------------
__global__ void wconv_kernel(const float* __restrict__ Wq, const float* __restrict__ Wk,
                             const float* __restrict__ Wv, const float* __restrict__ Wo,
                             __bf16* __restrict__ Wb) {
    const float* srcs[4] = {Wq, Wk, Wv, Wo};
    int m = blockIdx.x >> 6;
    int idx = (blockIdx.x & 63) * 256 + threadIdx.x;   // [0, 16384)
    float4 v = reinterpret_cast<const float4*>(srcs[m])[idx];
    bf16x4 o = { (__bf16)v.x, (__bf16)v.y, (__bf16)v.z, (__bf16)v.w };
    reinterpret_cast<bf16x4*>(Wb + m * 65536)[idx] = o;
}

// ---------------- kernel 1: gate + transpose to token-major bf16 ----------------
__global__ void prep_kernel(const float* __restrict__ x, const float* __restrict__ u,
                            const float* __restrict__ Wg, const float* __restrict__ bg,
                            __bf16* __restrict__ xT, __bf16* __restrict__ gxT) {
    __shared__ float tile[64][65];
    int b = blockIdx.z, c0 = blockIdx.y * 64, n0 = blockIdx.x * 64;
    int t = threadIdx.x;
    const float* xp = x + (b * C + c0) * N + n0;
    #pragma unroll
    for (int r = 0; r < 16; ++r) {
        int cl = r * 4 + (t >> 6);
        int nl = t & 63;
        tile[cl][nl] = xp[cl * N + nl];
    }
    __syncthreads();
    int cq = (t & 15) * 4;
    #pragma unroll
    for (int it = 0; it < 4; ++it) {
        int nl = it * 16 + (t >> 4);
        float uv = u[b * N + n0 + nl];
        bf16x4 xo, go;
        #pragma unroll
        for (int j = 0; j < 4; ++j) {
            int c = c0 + cq + j;
            float xv = tile[cq + j][nl];
            float gate = 1.0f - (Wg[c] * uv + bg[c]);
            xo[j] = (__bf16)xv;
            go[j] = (__bf16)(xv * gate);
        }
        int tok = b * N + n0 + nl;
        *reinterpret_cast<bf16x4*>(xT + (long)tok * C + c0 + cq) = xo;
        *reinterpret_cast<bf16x4*>(gxT + (long)tok * C + c0 + cq) = go;
    }
}

// ---------------- kernel 2: QKV projections (bf16 MFMA) ----------------
// Q[bh][n][d], K[bh][m][d] (pre-scaled by SCALE*log2e*(1-u[m])), V[bh][d][n]
__global__ __launch_bounds__(256) void qkv_kernel(const __bf16* __restrict__ Wb,
    const __bf16* __restrict__ xT, const __bf16* __restrict__ gxT,
    const float* __restrict__ bq, const float* __restrict__ bk, const float* __restrict__ bv,
    const float* __restrict__ u,
    __bf16* __restrict__ Q, __bf16* __restrict__ K, __bf16* __restrict__ V) {
    int proj = blockIdx.z;            // 0=q,1=k,2=v
    int o0 = blockIdx.y * 64;
    int t0 = blockIdx.x * 32;
    int wave = threadIdx.x >> 6, lane = threadIdx.x & 63;
    int g = lane >> 4, r = lane & 15;
    int ow = o0 + wave * 16;
    const __bf16* W = Wb + proj * 65536;
    const __bf16* inp = (proj == 2) ? xT : gxT;
    f32x4 acc[2] = {};
    for (int k = 0; k < 8; ++k) {
        bf16x8 a = load_bf8(W + (ow + r) * C + k * 32 + g * 8);
        #pragma unroll
        for (int tb = 0; tb < 2; ++tb) {
            bf16x8 bfr = load_bf8(inp + (long)(t0 + tb * 16 + r) * C + k * 32 + g * 8);
            acc[tb] = mfma32(a, bfr, acc[tb]);
        }
    }
    const float* bias = (proj == 0) ? bq : (proj == 1) ? bk : bv;
    float bvw[4];
    #pragma unroll
    for (int i = 0; i < 4; ++i) bvw[i] = bias[ow + g * 4 + i];
    int h = ow >> 5, d0 = (ow & 31) + g * 4;
    const float SC = 0.17677669529663687f * 1.4426950408889634f;  // SCALE * log2(e)
    #pragma unroll
    for (int tb = 0; tb < 2; ++tb) {
        int t = t0 + tb * 16 + r;
        int b = t / N, n = t % N;
        if (proj == 2) {
            #pragma unroll
            for (int i = 0; i < 4; ++i)
                V[((long)(b * 8 + h) * 32 + d0 + i) * N + n] = (__bf16)(acc[tb][i] + bvw[i]);
        } else {
            bf16x4 outv;
            if (proj == 1) {
                float scale = SC * (1.0f - u[t]);
                #pragma unroll
                for (int i = 0; i < 4; ++i) outv[i] = (__bf16)((acc[tb][i] + bvw[i]) * scale);
            } else {
                #pragma unroll
                for (int i = 0; i < 4; ++i) outv[i] = (__bf16)(acc[tb][i] + bvw[i]);
            }
            __bf16* dst = (proj == 0) ? Q : K;
            *reinterpret_cast<bf16x4*>(dst + ((long)(b * 8 + h) * N + n) * 32 + d0) = outv;
        }
    }
}

// ---------------- kernel 3: flash attention (LDS-staged, counted vmcnt) ----------------
// 64 q/block, 4 waves x 16q, full key range per block. Shared K/V tiles staged
// via global_load_lds (double-buffered, vmcnt(2), raw s_barrier). V stored with
// granule XOR swizzle (linear dest + inverse-swizzled SOURCE + swizzled read,
// rule #21). In-register P (K=16 PV), denom via ones-MFMA. No cross-wave combine.
__global__ __launch_bounds__(256) void attn_kernel(const __bf16* __restrict__ Q,
    const __bf16* __restrict__ K, const __bf16* __restrict__ V,
    __bf16* __restrict__ aoT) {
    __shared__ __bf16 sK[2][2048];   // [buf][64 keys x 32 d] linear, 4KB each
    __shared__ __bf16 sV[2][2048];   // [buf][32 d x 64 m] granule-swizzled rows
    int id = blockIdx.x;             // 576 = 8 xcd * 72
    int xcd = id & 7, j = id >> 3;   // j in [0,72)
    int bh = xcd + 8 * (j / 36);
    int qblk = j % 36;
    int wave = threadIdx.x >> 6, lane = threadIdx.x & 63;
    int g = lane >> 4, r = lane & 15;
    int q0w = qblk * 64 + wave * 16;
    const __bf16* Qg = Q + (long)bh * N * 32;
    const __bf16* Kg = K + (long)bh * N * 32;
    const __bf16* Vg = V + (long)bh * 32 * N;
    bf16x8 qf = load_bf8(Qg + (q0w + r) * 32 + g * 8);   // B-frag: Q^T[d][q]
    // staging source offsets (per lane)
    long ksrc = (long)(wave * 64 + lane) * 8;                       // + m0*32
    int vd = wave * 8 + (lane >> 3);                                // d-row 0..31
    long vsrc = (long)vd * N + ((lane & 7) ^ (lane >> 3)) * 8;      // + m0
    __bf16* sKb = &sK[0][0];
    __bf16* sVb = &sV[0][0];
    int sOff = wave * 512;           // this wave's staging quarter (elements)
    bf16x4 onesv;
    #pragma unroll
    for (int i = 0; i < 4; ++i) onesv[i] = (__bf16)1.0f;
    f32x4 oa0 = {}, oa1 = {}, oal = {};
    // prologue: stage tiles 0 and 1
    gload_lds16(Kg + ksrc, sKb + sOff);
    gload_lds16(Vg + vsrc, sVb + sOff);
    gload_lds16(Kg + 64 * 32 + ksrc, sKb + 2048 + sOff);
    gload_lds16(Vg + vsrc + 64, sVb + 2048 + sOff);
    int vswz = (r & 7) << 3;         // element-index granule XOR key
    for (int t = 0; t < 36; ++t) {
        if (t < 35) { VMCNT2(); } else { VMCNT0(); }
        __builtin_amdgcn_s_barrier();
        const __bf16* kb = sKb + (t & 1) * 2048;
        const __bf16* vb = sVb + (t & 1) * 2048;
        // ---- all LDS reads issued up front (counted lgkm waits by compiler) ----
        bf16x8 kc0 = load_bf8(kb + (0 * 16 + r) * 32 + g * 8);
        bf16x8 kc1 = load_bf8(kb + (1 * 16 + r) * 32 + g * 8);
        bf16x8 kc2 = load_bf8(kb + (2 * 16 + r) * 32 + g * 8);
        bf16x8 kc3 = load_bf8(kb + (3 * 16 + r) * 32 + g * 8);
        bf16x4 vf[4][2];
        #pragma unroll
        for (int tt = 0; tt < 4; ++tt)
            #pragma unroll
            for (int dt = 0; dt < 2; ++dt)
                vf[tt][dt] = *reinterpret_cast<const bf16x4*>(
                    vb + (dt * 16 + r) * 64 + ((tt * 16 + g * 4) ^ vswz));
        // ---- QK^T ----
        f32x4 z = {};
        __builtin_amdgcn_s_setprio(1);
        f32x4 s0 = mfma32(kc0, qf, z);   // S^T: lane(g,r) q=r, m=tt*16+g*4+i
        f32x4 s1 = mfma32(kc1, qf, z);
        f32x4 s2 = mfma32(kc2, qf, z);
        f32x4 s3 = mfma32(kc3, qf, z);
        __builtin_amdgcn_s_setprio(0);
        // ---- exp2 + pack ----
        bf16x4 pa0, pa1, pa2, pa3;
        #pragma unroll
        for (int i = 0; i < 4; ++i) pa0[i] = (__bf16)EXP2F(s0[i]);
        #pragma unroll
        for (int i = 0; i < 4; ++i) pa1[i] = (__bf16)EXP2F(s1[i]);
        #pragma unroll
        for (int i = 0; i < 4; ++i) pa2[i] = (__bf16)EXP2F(s2[i]);
        #pragma unroll
        for (int i = 0; i < 4; ++i) pa3[i] = (__bf16)EXP2F(s3[i]);
        // ---- PV (K=16, in-register P) + denominator via ones-row ----
        __builtin_amdgcn_s_setprio(1);
        oa0 = mfma16(vf[0][0], pa0, oa0);
        oa1 = mfma16(vf[0][1], pa0, oa1);
        oal = mfma16(onesv,    pa0, oal);
        oa0 = mfma16(vf[1][0], pa1, oa0);
        oa1 = mfma16(vf[1][1], pa1, oa1);
        oal = mfma16(onesv,    pa1, oal);
        oa0 = mfma16(vf[2][0], pa2, oa0);
        oa1 = mfma16(vf[2][1], pa2, oa1);
        oal = mfma16(onesv,    pa2, oal);
        oa0 = mfma16(vf[3][0], pa3, oa0);
        oa1 = mfma16(vf[3][1], pa3, oa1);
        oal = mfma16(onesv,    pa3, oal);
        __builtin_amdgcn_s_setprio(0);
        LGKM0();                          // all waves' reads of buf done
        __builtin_amdgcn_s_barrier();
        if (t < 34) {                     // stage t+2 into buf[t&1]
            long m0n = (long)(t + 2) * 64;
            gload_lds16(Kg + m0n * 32 + ksrc, sKb + (t & 1) * 2048 + sOff);
            gload_lds16(Vg + vsrc + m0n, sVb + (t & 1) * 2048 + sOff);
        }
    }
    // lane(g,r): oa[dt][i] = O[d = dt*16+g*4+i][q = q0w+r]; oal[i] = denom(q=q0w+r)
    float inv = 1.0f / oal[0];
    int b = bh >> 3, h = bh & 7;
    long tok = (long)b * N + q0w + r;
    bf16x4 ov0, ov1;
    #pragma unroll
    for (int i = 0; i < 4; ++i) ov0[i] = (__bf16)(oa0[i] * inv);
    #pragma unroll
    for (int i = 0; i < 4; ++i) ov1[i] = (__bf16)(oa1[i] * inv);
    *reinterpret_cast<bf16x4*>(aoT + tok * C + h * 32 + g * 4) = ov0;
    *reinterpret_cast<bf16x4*>(aoT + tok * C + h * 32 + 16 + g * 4) = ov1;
}

// ---------------- kernel 4: output projection + bias + residual ----------------
__global__ __launch_bounds__(256) void outp_kernel(const __bf16* __restrict__ Wb,
    const __bf16* __restrict__ aoT, const float* __restrict__ bo,
    const float* __restrict__ x, float* __restrict__ out) {
    int o0 = blockIdx.y * 64;
    int t0 = blockIdx.x * 32;
    int wave = threadIdx.x >> 6, lane = threadIdx.x & 63;
    int g = lane >> 4, r = lane & 15;
    int ow = o0 + wave * 16;
    const __bf16* W = Wb + 3 * 65536;   // Wo
    f32x4 acc[2] = {};
    for (int k = 0; k < 8; ++k) {
        bf16x8 a = load_bf8(W + (ow + r) * C + k * 32 + g * 8);
        #pragma unroll
        for (int tb = 0; tb < 2; ++tb) {
            bf16x8 bfr = load_bf8(aoT + (long)(t0 + tb * 16 + r) * C + k * 32 + g * 8);
            acc[tb] = mfma32(a, bfr, acc[tb]);
        }
    }
    float bvw[4];
    #pragma unroll
    for (int i = 0; i < 4; ++i) bvw[i] = bo[ow + g * 4 + i];
    #pragma unroll
    for (int tb = 0; tb < 2; ++tb) {
        int t = t0 + tb * 16 + r;
        int b = t / N, n = t % N;
        #pragma unroll
        for (int i = 0; i < 4; ++i) {
            long idx = ((long)b * C + ow + g * 4 + i) * N + n;
            out[idx] = acc[tb][i] + bvw[i] + x[idx];
        }
    }
}

extern "C" void kernel_launch(void* const* d_in, const int* in_sizes, int n_in,
                              void* d_out, int out_size, void* d_ws, size_t ws_size,
                              hipStream_t stream) {
    const float* x  = (const float*)d_in[0];
    const float* u  = (const float*)d_in[1];
    const float* Wq = (const float*)d_in[2];
    const float* bq = (const float*)d_in[3];
    const float* Wk = (const float*)d_in[4];
    const float* bk = (const float*)d_in[5];
    const float* Wv = (const float*)d_in[6];
    const float* bv = (const float*)d_in[7];
    const float* Wg = (const float*)d_in[8];
    const float* bg = (const float*)d_in[9];
    const float* Wo = (const float*)d_in[10];
    const float* bo = (const float*)d_in[11];
    float* out = (float*)d_out;

    char* ws = (char*)d_ws;
    size_t off = 0;
    auto alloc = [&](size_t bytes) {
        char* p = ws + off;
        off += (bytes + 255) & ~(size_t)255;
        return p;
    };
    __bf16* Wb  = (__bf16*)alloc((size_t)4 * 65536 * 2);
    __bf16* xT  = (__bf16*)alloc((size_t)T * C * 2);
    __bf16* gxT = (__bf16*)alloc((size_t)T * C * 2);
    __bf16* Qb  = (__bf16*)alloc((size_t)16 * N * 32 * 2);
    __bf16* Kb  = (__bf16*)alloc((size_t)16 * N * 32 * 2);
    __bf16* Vb  = (__bf16*)alloc((size_t)16 * N * 32 * 2);
    __bf16* aoT = (__bf16*)alloc((size_t)T * C * 2);

    wconv_kernel<<<256, 256, 0, stream>>>(Wq, Wk, Wv, Wo, Wb);
    prep_kernel<<<dim3(36, 4, 2), 256, 0, stream>>>(x, u, Wg, bg, xT, gxT);
    qkv_kernel<<<dim3(144, 4, 3), 256, 0, stream>>>(Wb, xT, gxT, bq, bk, bv, u, Qb, Kb, Vb);
    attn_kernel<<<576, 256, 0, stream>>>(Qb, Kb, Vb, aoT);
    outp_kernel<<<dim3(144, 4), 256, 0, stream>>>(Wb, aoT, bo, x, out);
}

// Round 8
// 78.971 us; speedup vs baseline: 1.8793x; 1.0277x over previous
//
#include <hip/hip_runtime.h>
#include <hip/hip_bf16.h>

typedef float f32x4 __attribute__((ext_vector_type(4)));
typedef __bf16 bf16x8 __attribute__((ext_vector_type(8)));
typedef __bf16 bf16x4 __attribute__((ext_vector_type(4)));
typedef short s16x4 __attribute__((ext_vector_type(4)));

constexpr int C = 256;
constexpr int N = 2304;           // 48*48 tokens per batch
constexpr int T = 2 * N;          // total tokens

#if __has_builtin(__builtin_amdgcn_exp2f)
#define EXP2F(x) __builtin_amdgcn_exp2f(x)
#else
#define EXP2F(x) exp2f(x)
#endif

__device__ __forceinline__ bf16x8 load_bf8(const __bf16* p) {
    return *reinterpret_cast<const bf16x8*>(p);
}

__device__ __forceinline__ f32x4 mfma32(bf16x8 a, bf16x8 b, f32x4 c) {
    return __builtin_amdgcn_mfma_f32_16x16x32_bf16(a, b, c, 0, 0, 0);
}

// K=16 MFMA: 4-element k-granules match the QK^T C/D output layout, so P feeds
// PV entirely in-register (no LDS redistribution). Verified correct R4-R7.
#if __has_builtin(__builtin_amdgcn_mfma_f32_16x16x16bf16_1k)
__device__ __forceinline__ f32x4 mfma16(bf16x4 a, bf16x4 b, f32x4 c) {
    return __builtin_amdgcn_mfma_f32_16x16x16bf16_1k(
        __builtin_bit_cast(s16x4, a), __builtin_bit_cast(s16x4, b), c, 0, 0, 0);
}
#else
__device__ __forceinline__ f32x4 mfma16(bf16x4 a, bf16x4 b, f32x4 c) {
    f32x4 d;
    asm volatile("v_mfma_f32_16x16x16_bf16 %0, %1, %2, %3"
                 : "=v"(d) : "v"(a), "v"(b), "v"(c));
    return d;
}
#endif

// async global->LDS, 16B per lane; dest = wave-uniform base + lane*16
__device__ __forceinline__ void gload_lds16(const __bf16* g, __bf16* l) {
    __builtin_amdgcn_global_load_lds(
        (const __attribute__((address_space(1))) void*)g,
        (__attribute__((address_space(3))) void*)l, 16, 0, 0);
}

#define VMCNT4() asm volatile("s_waitcnt vmcnt(4)" ::: "memory")
#define VMCNT0() asm volatile("s_waitcnt vmcnt(0)" ::: "memory")
#define LGKM0()  asm volatile("s_waitcnt lgkmcnt(0)" ::: "memory")

// ---------------- kernel 0: convert Wq/Wk/Wv/Wo to bf16 ----------------
__global__ void wconv_kernel(const float* __restrict__ Wq, const float* __restrict__ Wk,
                             const float* __restrict__ Wv, const float* __restrict__ Wo,
                             __bf16* __restrict__ Wb) {
    const float* srcs[4] = {Wq, Wk, Wv, Wo};
    int m = blockIdx.x >> 6;
    int idx = (blockIdx.x & 63) * 256 + threadIdx.x;   // [0, 16384)
    float4 v = reinterpret_cast<const float4*>(srcs[m])[idx];
    bf16x4 o = { (__bf16)v.x, (__bf16)v.y, (__bf16)v.z, (__bf16)v.w };
    reinterpret_cast<bf16x4*>(Wb + m * 65536)[idx] = o;
}

// ---------------- kernel 1: gate + transpose to token-major bf16 ----------------
__global__ void prep_kernel(const float* __restrict__ x, const float* __restrict__ u,
                            const float* __restrict__ Wg, const float* __restrict__ bg,
                            __bf16* __restrict__ xT, __bf16* __restrict__ gxT) {
    __shared__ float tile[64][65];
    int b = blockIdx.z, c0 = blockIdx.y * 64, n0 = blockIdx.x * 64;
    int t = threadIdx.x;
    const float* xp = x + (b * C + c0) * N + n0;
    #pragma unroll
    for (int r = 0; r < 16; ++r) {
        int cl = r * 4 + (t >> 6);
        int nl = t & 63;
        tile[cl][nl] = xp[cl * N + nl];
    }
    __syncthreads();
    int cq = (t & 15) * 4;
    #pragma unroll
    for (int it = 0; it < 4; ++it) {
        int nl = it * 16 + (t >> 4);
        float uv = u[b * N + n0 + nl];
        bf16x4 xo, go;
        #pragma unroll
        for (int j = 0; j < 4; ++j) {
            int c = c0 + cq + j;
            float xv = tile[cq + j][nl];
            float gate = 1.0f - (Wg[c] * uv + bg[c]);
            xo[j] = (__bf16)xv;
            go[j] = (__bf16)(xv * gate);
        }
        int tok = b * N + n0 + nl;
        *reinterpret_cast<bf16x4*>(xT + (long)tok * C + c0 + cq) = xo;
        *reinterpret_cast<bf16x4*>(gxT + (long)tok * C + c0 + cq) = go;
    }
}

// ---------------- kernel 2: QKV projections (bf16 MFMA) ----------------
// Q[bh][n][d], K[bh][m][d] (pre-scaled by SCALE*log2e*(1-u[m])), V[bh][d][n]
__global__ __launch_bounds__(256) void qkv_kernel(const __bf16* __restrict__ Wb,
    const __bf16* __restrict__ xT, const __bf16* __restrict__ gxT,
    const float* __restrict__ bq, const float* __restrict__ bk, const float* __restrict__ bv,
    const float* __restrict__ u,
    __bf16* __restrict__ Q, __bf16* __restrict__ K, __bf16* __restrict__ V) {
    int proj = blockIdx.z;            // 0=q,1=k,2=v
    int o0 = blockIdx.y * 64;
    int t0 = blockIdx.x * 32;
    int wave = threadIdx.x >> 6, lane = threadIdx.x & 63;
    int g = lane >> 4, r = lane & 15;
    int ow = o0 + wave * 16;
    const __bf16* W = Wb + proj * 65536;
    const __bf16* inp = (proj == 2) ? xT : gxT;
    f32x4 acc[2] = {};
    for (int k = 0; k < 8; ++k) {
        bf16x8 a = load_bf8(W + (ow + r) * C + k * 32 + g * 8);
        #pragma unroll
        for (int tb = 0; tb < 2; ++tb) {
            bf16x8 bfr = load_bf8(inp + (long)(t0 + tb * 16 + r) * C + k * 32 + g * 8);
            acc[tb] = mfma32(a, bfr, acc[tb]);
        }
    }
    const float* bias = (proj == 0) ? bq : (proj == 1) ? bk : bv;
    float bvw[4];
    #pragma unroll
    for (int i = 0; i < 4; ++i) bvw[i] = bias[ow + g * 4 + i];
    int h = ow >> 5, d0 = (ow & 31) + g * 4;
    const float SC = 0.17677669529663687f * 1.4426950408889634f;  // SCALE * log2(e)
    #pragma unroll
    for (int tb = 0; tb < 2; ++tb) {
        int t = t0 + tb * 16 + r;
        int b = t / N, n = t % N;
        if (proj == 2) {
            #pragma unroll
            for (int i = 0; i < 4; ++i)
                V[((long)(b * 8 + h) * 32 + d0 + i) * N + n] = (__bf16)(acc[tb][i] + bvw[i]);
        } else {
            bf16x4 outv;
            if (proj == 1) {
                float scale = SC * (1.0f - u[t]);
                #pragma unroll
                for (int i = 0; i < 4; ++i) outv[i] = (__bf16)((acc[tb][i] + bvw[i]) * scale);
            } else {
                #pragma unroll
                for (int i = 0; i < 4; ++i) outv[i] = (__bf16)(acc[tb][i] + bvw[i]);
            }
            __bf16* dst = (proj == 0) ? Q : K;
            *reinterpret_cast<bf16x4*>(dst + ((long)(b * 8 + h) * N + n) * 32 + d0) = outv;
        }
    }
}

// ---------------- kernel 3: flash attention ----------------
// 32q/block (2 waves x 16q), full keys. Triple-buffered K/V tiles via
// global_load_lds, ONE raw s_barrier per iter, counted vmcnt(4). V stored
// chunk-swizzled: phys chunk cp of row rr holds logical chunk cp^((rr>>1)&7)
// (key avoids g-bits -> balanced 4 accesses/bank on read; 16B-granular so
// DMA chunks stay contiguous). In-register P (K=16 PV), denom via ones-MFMA.
__global__ __launch_bounds__(128) void attn_kernel(const __bf16* __restrict__ Q,
    const __bf16* __restrict__ K, const __bf16* __restrict__ V,
    __bf16* __restrict__ aoT) {
    __shared__ __bf16 sK[3][2048];   // [buf][64 keys x 32 d] linear
    __shared__ __bf16 sV[3][2048];   // [buf][32 d x 64 m] chunk-swizzled rows
    int id = blockIdx.x;             // 1152 = 8 xcd * 144
    int xcd = id & 7, j = id >> 3;   // j in [0,144)
    int bh = xcd + 8 * (j / 72);
    int qblk = j % 72;
    int tid = threadIdx.x;           // 0..127
    int wave = tid >> 6, lane = tid & 63;
    int g = lane >> 4, r = lane & 15;
    int q0w = qblk * 32 + wave * 16;
    const __bf16* Qg = Q + (long)bh * N * 32;
    const __bf16* Kg = K + (long)bh * N * 32;
    const __bf16* Vg = V + (long)bh * 32 * N;
    bf16x8 qf = load_bf8(Qg + (q0w + r) * 32 + g * 8);   // B-frag: Q^T[d][q]
    // staging sources: virtual threads tid and tid+128, 16B each
    long ka = (long)tid * 8;                         // K elems (linear)
    int rrA = tid >> 3;                              // V d-row 0..15 (A), +16 (B)
    int clA = (tid & 7) ^ ((tid >> 4) & 7);          // logical chunk (same key for B)
    long va = (long)rrA * N + clA * 8;
    int so = wave * 512;                             // wave staging base (elems)
    auto STAGE = [&](long m0, __bf16* kd, __bf16* vd) {
        gload_lds16(Kg + m0 * 32 + ka,          kd + so);
        gload_lds16(Kg + m0 * 32 + 1024 + ka,   kd + 1024 + so);
        gload_lds16(Vg + va + m0,               vd + so);
        gload_lds16(Vg + va + 16 * N + m0,      vd + 1024 + so);
    };
    __bf16 *kA = &sK[0][0], *kB = &sK[1][0], *kC = &sK[2][0];
    __bf16 *vA = &sV[0][0], *vB = &sV[1][0], *vC = &sV[2][0];
    bf16x4 onesv;
    #pragma unroll
    for (int i = 0; i < 4; ++i) onesv[i] = (__bf16)1.0f;
    f32x4 oa0 = {}, oa1 = {}, oal = {};
    STAGE(0, kA, vA);
    STAGE(64, kB, vB);
    int k2r = (r >> 1) & 7;          // V read swizzle key (same for dt=0,1)
    for (int t = 0; t < 36; ++t) {
        LGKM0();                     // prev iter's LDS reads landed (WAR safety)
        if (t < 34) { VMCNT4(); } else { VMCNT0(); }
        __builtin_amdgcn_s_barrier();
        if (t < 34) STAGE((long)(t + 2) * 64, kC, vC);
        // ---- LDS reads ----
        bf16x8 kc0 = load_bf8(kA + (0 * 16 + r) * 32 + g * 8);
        bf16x8 kc1 = load_bf8(kA + (1 * 16 + r) * 32 + g * 8);
        bf16x8 kc2 = load_bf8(kA + (2 * 16 + r) * 32 + g * 8);
        bf16x8 kc3 = load_bf8(kA + (3 * 16 + r) * 32 + g * 8);
        bf16x4 vf[4][2];
        #pragma unroll
        for (int tt = 0; tt < 4; ++tt) {
            int pg = (((tt * 2 + (g >> 1)) ^ k2r) << 1) | (g & 1);
            #pragma unroll
            for (int dt = 0; dt < 2; ++dt)
                vf[tt][dt] = *reinterpret_cast<const bf16x4*>(
                    vA + (dt * 16 + r) * 64 + pg * 4);
        }
        // ---- QK^T ----
        f32x4 z = {};
        __builtin_amdgcn_s_setprio(1);
        f32x4 s0 = mfma32(kc0, qf, z);   // S^T: lane(g,r) q=r, m=tt*16+g*4+i
        f32x4 s1 = mfma32(kc1, qf, z);
        f32x4 s2 = mfma32(kc2, qf, z);
        f32x4 s3 = mfma32(kc3, qf, z);
        __builtin_amdgcn_s_setprio(0);
        // ---- exp2 + pack (scores pre-scaled by log2e) ----
        bf16x4 pa0, pa1, pa2, pa3;
        #pragma unroll
        for (int i = 0; i < 4; ++i) pa0[i] = (__bf16)EXP2F(s0[i]);
        #pragma unroll
        for (int i = 0; i < 4; ++i) pa1[i] = (__bf16)EXP2F(s1[i]);
        #pragma unroll
        for (int i = 0; i < 4; ++i) pa2[i] = (__bf16)EXP2F(s2[i]);
        #pragma unroll
        for (int i = 0; i < 4; ++i) pa3[i] = (__bf16)EXP2F(s3[i]);
        // ---- PV (K=16, in-register P) + denominator via ones-row ----
        __builtin_amdgcn_s_setprio(1);
        oa0 = mfma16(vf[0][0], pa0, oa0);
        oa1 = mfma16(vf[0][1], pa0, oa1);
        oal = mfma16(onesv,    pa0, oal);
        oa0 = mfma16(vf[1][0], pa1, oa0);
        oa1 = mfma16(vf[1][1], pa1, oa1);
        oal = mfma16(onesv,    pa1, oal);
        oa0 = mfma16(vf[2][0], pa2, oa0);
        oa1 = mfma16(vf[2][1], pa2, oa1);
        oal = mfma16(onesv,    pa2, oal);
        oa0 = mfma16(vf[3][0], pa3, oa0);
        oa1 = mfma16(vf[3][1], pa3, oa1);
        oal = mfma16(onesv,    pa3, oal);
        __builtin_amdgcn_s_setprio(0);
        // rotate buffers: read B next, stage into old A
        __bf16* tk = kA; kA = kB; kB = kC; kC = tk;
        __bf16* tv = vA; vA = vB; vB = vC; vC = tv;
    }
    // lane(g,r): oa[dt][i] = O[d=dt*16+g*4+i][q=q0w+r]; oal[i] = denom(q)
    float inv = 1.0f / oal[0];
    int b = bh >> 3, h = bh & 7;
    long tok = (long)b * N + q0w + r;
    bf16x4 ov0, ov1;
    #pragma unroll
    for (int i = 0; i < 4; ++i) ov0[i] = (__bf16)(oa0[i] * inv);
    #pragma unroll
    for (int i = 0; i < 4; ++i) ov1[i] = (__bf16)(oa1[i] * inv);
    *reinterpret_cast<bf16x4*>(aoT + tok * C + h * 32 + g * 4) = ov0;
    *reinterpret_cast<bf16x4*>(aoT + tok * C + h * 32 + 16 + g * 4) = ov1;
}

// ---------------- kernel 4: output projection + bias + residual ----------------
__global__ __launch_bounds__(256) void outp_kernel(const __bf16* __restrict__ Wb,
    const __bf16* __restrict__ aoT, const float* __restrict__ bo,
    const float* __restrict__ x, float* __restrict__ out) {
    int o0 = blockIdx.y * 64;
    int t0 = blockIdx.x * 32;
    int wave = threadIdx.x >> 6, lane = threadIdx.x & 63;
    int g = lane >> 4, r = lane & 15;
    int ow = o0 + wave * 16;
    const __bf16* W = Wb + 3 * 65536;   // Wo
    f32x4 acc[2] = {};
    for (int k = 0; k < 8; ++k) {
        bf16x8 a = load_bf8(W + (ow + r) * C + k * 32 + g * 8);
        #pragma unroll
        for (int tb = 0; tb < 2; ++tb) {
            bf16x8 bfr = load_bf8(aoT + (long)(t0 + tb * 16 + r) * C + k * 32 + g * 8);
            acc[tb] = mfma32(a, bfr, acc[tb]);
        }
    }
    float bvw[4];
    #pragma unroll
    for (int i = 0; i < 4; ++i) bvw[i] = bo[ow + g * 4 + i];
    #pragma unroll
    for (int tb = 0; tb < 2; ++tb) {
        int t = t0 + tb * 16 + r;
        int b = t / N, n = t % N;
        #pragma unroll
        for (int i = 0; i < 4; ++i) {
            long idx = ((long)b * C + ow + g * 4 + i) * N + n;
            out[idx] = acc[tb][i] + bvw[i] + x[idx];
        }
    }
}

extern "C" void kernel_launch(void* const* d_in, const int* in_sizes, int n_in,
                              void* d_out, int out_size, void* d_ws, size_t ws_size,
                              hipStream_t stream) {
    const float* x  = (const float*)d_in[0];
    const float* u  = (const float*)d_in[1];
    const float* Wq = (const float*)d_in[2];
    const float* bq = (const float*)d_in[3];
    const float* Wk = (const float*)d_in[4];
    const float* bk = (const float*)d_in[5];
    const float* Wv = (const float*)d_in[6];
    const float* bv = (const float*)d_in[7];
    const float* Wg = (const float*)d_in[8];
    const float* bg = (const float*)d_in[9];
    const float* Wo = (const float*)d_in[10];
    const float* bo = (const float*)d_in[11];
    float* out = (float*)d_out;

    char* ws = (char*)d_ws;
    size_t off = 0;
    auto alloc = [&](size_t bytes) {
        char* p = ws + off;
        off += (bytes + 255) & ~(size_t)255;
        return p;
    };
    __bf16* Wb  = (__bf16*)alloc((size_t)4 * 65536 * 2);
    __bf16* xT  = (__bf16*)alloc((size_t)T * C * 2);
    __bf16* gxT = (__bf16*)alloc((size_t)T * C * 2);
    __bf16* Qb  = (__bf16*)alloc((size_t)16 * N * 32 * 2);
    __bf16* Kb  = (__bf16*)alloc((size_t)16 * N * 32 * 2);
    __bf16* Vb  = (__bf16*)alloc((size_t)16 * N * 32 * 2);
    __bf16* aoT = (__bf16*)alloc((size_t)T * C * 2);

    wconv_kernel<<<256, 256, 0, stream>>>(Wq, Wk, Wv, Wo, Wb);
    prep_kernel<<<dim3(36, 4, 2), 256, 0, stream>>>(x, u, Wg, bg, xT, gxT);
    qkv_kernel<<<dim3(144, 4, 3), 256, 0, stream>>>(Wb, xT, gxT, bq, bk, bv, u, Qb, Kb, Vb);
    attn_kernel<<<1152, 128, 0, stream>>>(Qb, Kb, Vb, aoT);
    outp_kernel<<<dim3(144, 4), 256, 0, stream>>>(Wb, aoT, bo, x, out);
}

// Round 9
// 78.757 us; speedup vs baseline: 1.8844x; 1.0027x over previous
//
#include <hip/hip_runtime.h>
#include <hip/hip_bf16.h>

typedef float f32x4 __attribute__((ext_vector_type(4)));
typedef __bf16 bf16x8 __attribute__((ext_vector_type(8)));
typedef __bf16 bf16x4 __attribute__((ext_vector_type(4)));
typedef short s16x4 __attribute__((ext_vector_type(4)));

constexpr int C = 256;
constexpr int N = 2304;           // 48*48 tokens per batch
constexpr int T = 2 * N;          // total tokens

#if __has_builtin(__builtin_amdgcn_exp2f)
#define EXP2F(x) __builtin_amdgcn_exp2f(x)
#else
#define EXP2F(x) exp2f(x)
#endif

__device__ __forceinline__ bf16x8 load_bf8(const __bf16* p) {
    return *reinterpret_cast<const bf16x8*>(p);
}

__device__ __forceinline__ f32x4 mfma32(bf16x8 a, bf16x8 b, f32x4 c) {
    return __builtin_amdgcn_mfma_f32_16x16x32_bf16(a, b, c, 0, 0, 0);
}

// K=16 MFMA: 4-element k-granules match the QK^T C/D output layout, so P feeds
// PV entirely in-register (no LDS redistribution). Verified correct R4-R8.
#if __has_builtin(__builtin_amdgcn_mfma_f32_16x16x16bf16_1k)
__device__ __forceinline__ f32x4 mfma16(bf16x4 a, bf16x4 b, f32x4 c) {
    return __builtin_amdgcn_mfma_f32_16x16x16bf16_1k(
        __builtin_bit_cast(s16x4, a), __builtin_bit_cast(s16x4, b), c, 0, 0, 0);
}
#else
__device__ __forceinline__ f32x4 mfma16(bf16x4 a, bf16x4 b, f32x4 c) {
    f32x4 d;
    asm volatile("v_mfma_f32_16x16x16_bf16 %0, %1, %2, %3"
                 : "=v"(d) : "v"(a), "v"(b), "v"(c));
    return d;
}
#endif

// async global->LDS, 16B per lane; dest = wave-uniform base + lane*16
__device__ __forceinline__ void gload_lds16(const __bf16* g, __bf16* l) {
    __builtin_amdgcn_global_load_lds(
        (const __attribute__((address_space(1))) void*)g,
        (__attribute__((address_space(3))) void*)l, 16, 0, 0);
}

#define VMCNT0() asm volatile("s_waitcnt vmcnt(0)" ::: "memory")
#define LGKM0()  asm volatile("s_waitcnt lgkmcnt(0)" ::: "memory")

// ---------------- kernel 0: convert Wq/Wk/Wv/Wo to bf16 ----------------
__global__ void wconv_kernel(const float* __restrict__ Wq, const float* __restrict__ Wk,
                             const float* __restrict__ Wv, const float* __restrict__ Wo,
                             __bf16* __restrict__ Wb) {
    const float* srcs[4] = {Wq, Wk, Wv, Wo};
    int m = blockIdx.x >> 6;
    int idx = (blockIdx.x & 63) * 256 + threadIdx.x;   // [0, 16384)
    float4 v = reinterpret_cast<const float4*>(srcs[m])[idx];
    bf16x4 o = { (__bf16)v.x, (__bf16)v.y, (__bf16)v.z, (__bf16)v.w };
    reinterpret_cast<bf16x4*>(Wb + m * 65536)[idx] = o;
}

// ---------------- kernel 1: gate + transpose (32-row tiles, 576 blocks) ----------------
__global__ void prep_kernel(const float* __restrict__ x, const float* __restrict__ u,
                            const float* __restrict__ Wg, const float* __restrict__ bg,
                            __bf16* __restrict__ xT, __bf16* __restrict__ gxT) {
    __shared__ float tile[32][65];
    int b = blockIdx.z, c0 = blockIdx.y * 32, n0 = blockIdx.x * 64;
    int t = threadIdx.x;
    const float* xp = x + (b * C + c0) * N + n0;
    #pragma unroll
    for (int r = 0; r < 8; ++r) {
        int cl = r * 4 + (t >> 6);
        int nl = t & 63;
        tile[cl][nl] = xp[cl * N + nl];
    }
    __syncthreads();
    int cq = (t & 7) * 4;
    #pragma unroll
    for (int it = 0; it < 2; ++it) {
        int nl = it * 32 + (t >> 3);
        float uv = u[b * N + n0 + nl];
        bf16x4 xo, go;
        #pragma unroll
        for (int j = 0; j < 4; ++j) {
            int c = c0 + cq + j;
            float xv = tile[cq + j][nl];
            float gate = 1.0f - (Wg[c] * uv + bg[c]);
            xo[j] = (__bf16)xv;
            go[j] = (__bf16)(xv * gate);
        }
        int tok = b * N + n0 + nl;
        *reinterpret_cast<bf16x4*>(xT + (long)tok * C + c0 + cq) = xo;
        *reinterpret_cast<bf16x4*>(gxT + (long)tok * C + c0 + cq) = go;
    }
}

// ---------------- kernel 2: QKV projections (bf16 MFMA) ----------------
// Q[bh][n][d], K[bh][m][d] (pre-scaled by SCALE*log2e*(1-u[m])), V[bh][d][n]
__global__ __launch_bounds__(256) void qkv_kernel(const __bf16* __restrict__ Wb,
    const __bf16* __restrict__ xT, const __bf16* __restrict__ gxT,
    const float* __restrict__ bq, const float* __restrict__ bk, const float* __restrict__ bv,
    const float* __restrict__ u,
    __bf16* __restrict__ Q, __bf16* __restrict__ K, __bf16* __restrict__ V) {
    int proj = blockIdx.z;            // 0=q,1=k,2=v
    int o0 = blockIdx.y * 64;
    int t0 = blockIdx.x * 32;
    int wave = threadIdx.x >> 6, lane = threadIdx.x & 63;
    int g = lane >> 4, r = lane & 15;
    int ow = o0 + wave * 16;
    const __bf16* W = Wb + proj * 65536;
    const __bf16* inp = (proj == 2) ? xT : gxT;
    f32x4 acc[2] = {};
    for (int k = 0; k < 8; ++k) {
        bf16x8 a = load_bf8(W + (ow + r) * C + k * 32 + g * 8);
        #pragma unroll
        for (int tb = 0; tb < 2; ++tb) {
            bf16x8 bfr = load_bf8(inp + (long)(t0 + tb * 16 + r) * C + k * 32 + g * 8);
            acc[tb] = mfma32(a, bfr, acc[tb]);
        }
    }
    const float* bias = (proj == 0) ? bq : (proj == 1) ? bk : bv;
    float bvw[4];
    #pragma unroll
    for (int i = 0; i < 4; ++i) bvw[i] = bias[ow + g * 4 + i];
    int h = ow >> 5, d0 = (ow & 31) + g * 4;
    const float SC = 0.17677669529663687f * 1.4426950408889634f;  // SCALE * log2(e)
    #pragma unroll
    for (int tb = 0; tb < 2; ++tb) {
        int t = t0 + tb * 16 + r;
        int b = t / N, n = t % N;
        if (proj == 2) {
            #pragma unroll
            for (int i = 0; i < 4; ++i)
                V[((long)(b * 8 + h) * 32 + d0 + i) * N + n] = (__bf16)(acc[tb][i] + bvw[i]);
        } else {
            bf16x4 outv;
            if (proj == 1) {
                float scale = SC * (1.0f - u[t]);
                #pragma unroll
                for (int i = 0; i < 4; ++i) outv[i] = (__bf16)((acc[tb][i] + bvw[i]) * scale);
            } else {
                #pragma unroll
                for (int i = 0; i < 4; ++i) outv[i] = (__bf16)(acc[tb][i] + bvw[i]);
            }
            __bf16* dst = (proj == 0) ? Q : K;
            *reinterpret_cast<bf16x4*>(dst + ((long)(b * 8 + h) * N + n) * 32 + d0) = outv;
        }
    }
}

// ---------------- kernel 3: flash attention ----------------
// 4 waves/block: wave-pair p owns keys [p*1152,(p+1)*1152), waves within a pair
// own q-tiles 0/1 of a 32-query block. Two K/V LDS streams (one per pair),
// double-buffered, staged by global_load_lds; ONE s_barrier/iter; vmcnt(0)
// placed BEFORE the barrier so the partner wave's half-tile is landed too
// (prefetch issued after previous barrier -> a full iteration of cover).
// V chunk-swizzle identical to R8 (verified): phys chunk cp of row rr holds
// logical chunk cp^((rr>>1)&7). In-register P (K=16 PV), denom via ones-MFMA.
// Epilogue: partials combined via retired sK region.
__global__ __launch_bounds__(256) void attn_kernel(const __bf16* __restrict__ Q,
    const __bf16* __restrict__ K, const __bf16* __restrict__ V,
    __bf16* __restrict__ aoT) {
    __shared__ __bf16 sK[2][2][2048];   // [pair][buf][64 keys x 32 d] linear
    __shared__ __bf16 sV[2][2][2048];   // [pair][buf][32 d x 64 m] chunk-swizzled
    int id = blockIdx.x;                // 1152 = 8 xcd * 144
    int xcd = id & 7, j = id >> 3;      // j in [0,144)
    int bh = xcd + 8 * (j / 72);
    int qblk = j % 72;
    int tid = threadIdx.x;
    int wave = tid >> 6, lane = tid & 63;
    int wp = wave & 1, pair = wave >> 1;
    int g = lane >> 4, r = lane & 15;
    int q0 = qblk * 32;
    const __bf16* Qg = Q + (long)bh * N * 32;
    const __bf16* Kg = K + (long)bh * N * 32 + (long)pair * 1152 * 32;
    const __bf16* Vg = V + (long)bh * 32 * N + pair * 1152;
    bf16x8 qf = load_bf8(Qg + (q0 + wp * 16 + r) * 32 + g * 8);   // B-frag Q^T
    // staging sources (per lane); each wave stages half of each 4KB tile
    long ksrc = (long)(wp * 64 + lane) * 8;
    int rr1 = wp * 8 + (lane >> 3);
    long vsrc0 = (long)rr1 * N + ((lane & 7) ^ ((rr1 >> 1) & 7)) * 8;
    int rr2 = 16 + rr1;
    long vsrc1 = (long)rr2 * N + ((lane & 7) ^ ((rr2 >> 1) & 7)) * 8;
    __bf16* kb0 = &sK[pair][0][0];
    __bf16* kb1 = &sK[pair][1][0];
    __bf16* vb0 = &sV[pair][0][0];
    __bf16* vb1 = &sV[pair][1][0];
    auto STAGE = [&](long m0, __bf16* kd, __bf16* vd) {
        gload_lds16(Kg + m0 * 32 + ksrc,        kd + wp * 512);
        gload_lds16(Kg + m0 * 32 + 1024 + ksrc, kd + 1024 + wp * 512);
        gload_lds16(Vg + vsrc0 + m0,            vd + wp * 512);
        gload_lds16(Vg + vsrc1 + m0,            vd + 1024 + wp * 512);
    };
    bf16x4 onesv;
    #pragma unroll
    for (int i = 0; i < 4; ++i) onesv[i] = (__bf16)1.0f;
    f32x4 oa0 = {}, oa1 = {}, oal = {};
    int k2r = (r >> 1) & 7;          // V read swizzle key
    STAGE(0, kb0, vb0);
    for (int t = 0; t < 18; ++t) {
        LGKM0();                     // my reads of tile t-1 done (WAR)
        VMCNT0();                    // my stage(t) portion landed
        __builtin_amdgcn_s_barrier();// partner's too; all reads of t-1 done
        const __bf16* kb = (t & 1) ? kb1 : kb0;
        const __bf16* vb = (t & 1) ? vb1 : vb0;
        if (t < 17)                  // prefetch t+1 into the buffer read at t-1
            STAGE((long)(t + 1) * 64, (t & 1) ? kb0 : kb1, (t & 1) ? vb0 : vb1);
        // ---- LDS reads ----
        bf16x8 kc0 = load_bf8(kb + (0 * 16 + r) * 32 + g * 8);
        bf16x8 kc1 = load_bf8(kb + (1 * 16 + r) * 32 + g * 8);
        bf16x8 kc2 = load_bf8(kb + (2 * 16 + r) * 32 + g * 8);
        bf16x8 kc3 = load_bf8(kb + (3 * 16 + r) * 32 + g * 8);
        bf16x4 vf[4][2];
        #pragma unroll
        for (int tt = 0; tt < 4; ++tt) {
            int pg = (((tt * 2 + (g >> 1)) ^ k2r) << 1) | (g & 1);
            #pragma unroll
            for (int dt = 0; dt < 2; ++dt)
                vf[tt][dt] = *reinterpret_cast<const bf16x4*>(
                    vb + (dt * 16 + r) * 64 + pg * 4);
        }
        // ---- QK^T ----
        f32x4 z = {};
        __builtin_amdgcn_s_setprio(1);
        f32x4 s0 = mfma32(kc0, qf, z);   // S^T: lane(g,r) q=r, m=tt*16+g*4+i
        f32x4 s1 = mfma32(kc1, qf, z);
        f32x4 s2 = mfma32(kc2, qf, z);
        f32x4 s3 = mfma32(kc3, qf, z);
        __builtin_amdgcn_s_setprio(0);
        // ---- exp2 + pack (scores pre-scaled by log2e) ----
        bf16x4 pa0, pa1, pa2, pa3;
        #pragma unroll
        for (int i = 0; i < 4; ++i) pa0[i] = (__bf16)EXP2F(s0[i]);
        #pragma unroll
        for (int i = 0; i < 4; ++i) pa1[i] = (__bf16)EXP2F(s1[i]);
        #pragma unroll
        for (int i = 0; i < 4; ++i) pa2[i] = (__bf16)EXP2F(s2[i]);
        #pragma unroll
        for (int i = 0; i < 4; ++i) pa3[i] = (__bf16)EXP2F(s3[i]);
        // ---- PV (K=16, in-register P) + denominator via ones-row ----
        __builtin_amdgcn_s_setprio(1);
        oa0 = mfma16(vf[0][0], pa0, oa0);
        oa1 = mfma16(vf[0][1], pa0, oa1);
        oal = mfma16(onesv,    pa0, oal);
        oa0 = mfma16(vf[1][0], pa1, oa0);
        oa1 = mfma16(vf[1][1], pa1, oa1);
        oal = mfma16(onesv,    pa1, oal);
        oa0 = mfma16(vf[2][0], pa2, oa0);
        oa1 = mfma16(vf[2][1], pa2, oa1);
        oal = mfma16(onesv,    pa2, oal);
        oa0 = mfma16(vf[3][0], pa3, oa0);
        oa1 = mfma16(vf[3][1], pa3, oa1);
        oal = mfma16(onesv,    pa3, oal);
        __builtin_amdgcn_s_setprio(0);
    }
    // combine the two key-halves via retired sK region (all reads drained:
    // every wave's last ds_reads completed before its MFMAs, MFMAs before here)
    __builtin_amdgcn_s_barrier();
    float* F = reinterpret_cast<float*>(&sK[0][0][0]);   // 4096 f32 available
    // lane(g,r): oa0[i]=O[d=g*4+i][q=r], oa1[i]=O[d=16+g*4+i][q=r], oal=denom
    *reinterpret_cast<f32x4*>(F + wave * 512 + r * 32 + g * 4) = oa0;
    *reinterpret_cast<f32x4*>(F + wave * 512 + r * 32 + 16 + g * 4) = oa1;
    if (g == 0) F[2048 + wave * 16 + r] = oal[0];
    __builtin_amdgcn_s_barrier();
    if (tid < 128) {
        int q = tid >> 2;            // 0..31
        int wpq = q >> 4, qq = q & 15;
        int d8 = (tid & 3) * 8;
        int base0 = wpq * 512 + qq * 32 + d8;
        int base1 = (wpq + 2) * 512 + qq * 32 + d8;
        f32x4 a0 = *reinterpret_cast<f32x4*>(F + base0) +
                   *reinterpret_cast<f32x4*>(F + base1);
        f32x4 a1 = *reinterpret_cast<f32x4*>(F + base0 + 4) +
                   *reinterpret_cast<f32x4*>(F + base1 + 4);
        float l = F[2048 + wpq * 16 + qq] + F[2048 + (wpq + 2) * 16 + qq];
        float inv = 1.0f / l;
        bf16x8 ov;
        #pragma unroll
        for (int i = 0; i < 4; ++i) {
            ov[i] = (__bf16)(a0[i] * inv);
            ov[4 + i] = (__bf16)(a1[i] * inv);
        }
        int b = bh >> 3, h = bh & 7;
        *reinterpret_cast<bf16x8*>(aoT + (long)(b * N + q0 + q) * C + h * 32 + d8) = ov;
    }
}

// ---------------- kernel 4: output projection + bias + residual ----------------
// 16-token tiles (grid 288x4 -> 4608 waves) for latency hiding.
__global__ __launch_bounds__(256) void outp_kernel(const __bf16* __restrict__ Wb,
    const __bf16* __restrict__ aoT, const float* __restrict__ bo,
    const float* __restrict__ x, float* __restrict__ out) {
    int o0 = blockIdx.y * 64;
    int t0 = blockIdx.x * 16;
    int wave = threadIdx.x >> 6, lane = threadIdx.x & 63;
    int g = lane >> 4, r = lane & 15;
    int ow = o0 + wave * 16;
    const __bf16* W = Wb + 3 * 65536;   // Wo
    f32x4 acc = {};
    for (int k = 0; k < 8; ++k) {
        bf16x8 a = load_bf8(W + (ow + r) * C + k * 32 + g * 8);
        bf16x8 bfr = load_bf8(aoT + (long)(t0 + r) * C + k * 32 + g * 8);
        acc = mfma32(a, bfr, acc);
    }
    float bvw[4];
    #pragma unroll
    for (int i = 0; i < 4; ++i) bvw[i] = bo[ow + g * 4 + i];
    int t = t0 + r;
    int b = t / N, n = t % N;
    #pragma unroll
    for (int i = 0; i < 4; ++i) {
        long idx = ((long)b * C + ow + g * 4 + i) * N + n;
        out[idx] = acc[i] + bvw[i] + x[idx];
    }
}

extern "C" void kernel_launch(void* const* d_in, const int* in_sizes, int n_in,
                              void* d_out, int out_size, void* d_ws, size_t ws_size,
                              hipStream_t stream) {
    const float* x  = (const float*)d_in[0];
    const float* u  = (const float*)d_in[1];
    const float* Wq = (const float*)d_in[2];
    const float* bq = (const float*)d_in[3];
    const float* Wk = (const float*)d_in[4];
    const float* bk = (const float*)d_in[5];
    const float* Wv = (const float*)d_in[6];
    const float* bv = (const float*)d_in[7];
    const float* Wg = (const float*)d_in[8];
    const float* bg = (const float*)d_in[9];
    const float* Wo = (const float*)d_in[10];
    const float* bo = (const float*)d_in[11];
    float* out = (float*)d_out;

    char* ws = (char*)d_ws;
    size_t off = 0;
    auto alloc = [&](size_t bytes) {
        char* p = ws + off;
        off += (bytes + 255) & ~(size_t)255;
        return p;
    };
    __bf16* Wb  = (__bf16*)alloc((size_t)4 * 65536 * 2);
    __bf16* xT  = (__bf16*)alloc((size_t)T * C * 2);
    __bf16* gxT = (__bf16*)alloc((size_t)T * C * 2);
    __bf16* Qb  = (__bf16*)alloc((size_t)16 * N * 32 * 2);
    __bf16* Kb  = (__bf16*)alloc((size_t)16 * N * 32 * 2);
    __bf16* Vb  = (__bf16*)alloc((size_t)16 * N * 32 * 2);
    __bf16* aoT = (__bf16*)alloc((size_t)T * C * 2);

    wconv_kernel<<<256, 256, 0, stream>>>(Wq, Wk, Wv, Wo, Wb);
    prep_kernel<<<dim3(36, 8, 2), 256, 0, stream>>>(x, u, Wg, bg, xT, gxT);
    qkv_kernel<<<dim3(144, 4, 3), 256, 0, stream>>>(Wb, xT, gxT, bq, bk, bv, u, Qb, Kb, Vb);
    attn_kernel<<<1152, 256, 0, stream>>>(Qb, Kb, Vb, aoT);
    outp_kernel<<<dim3(288, 4), 256, 0, stream>>>(Wb, aoT, bo, x, out);
}